// Round 1
// baseline (241.730 us; speedup 1.0000x reference)
//
#include <hip/hip_runtime.h>

#define TDIM 4096

struct Fr { float r[9]; float p[3]; float q[4]; };

__device__ __forceinline__ void frame_root(Fr& f, float w, float x, float y, float z) {
  f.r[0]=1.f; f.r[1]=0.f; f.r[2]=0.f;
  f.r[3]=0.f; f.r[4]=1.f; f.r[5]=0.f;
  f.r[6]=0.f; f.r[7]=0.f; f.r[8]=1.f;
  f.p[0]=0.f; f.p[1]=0.f; f.p[2]=0.f;
  f.q[0]=w; f.q[1]=x; f.q[2]=y; f.q[3]=z;
}

// advance frame f by joint with raw (denormed) quat q and bone offset off
__device__ __forceinline__ void step(Fr& f, const float q[4], const float off[3]) {
  // loc = conj(f.q) * q   (f.q is the parent joint's global-data quat)
  float lw = f.q[0]*q[0] + f.q[1]*q[1] + f.q[2]*q[2] + f.q[3]*q[3];
  float lx = f.q[0]*q[1] - f.q[1]*q[0] - f.q[2]*q[3] + f.q[3]*q[2];
  float ly = f.q[0]*q[2] + f.q[1]*q[3] - f.q[2]*q[0] - f.q[3]*q[1];
  float lz = f.q[0]*q[3] - f.q[1]*q[2] + f.q[2]*q[1] - f.q[3]*q[0];
  float n  = sqrtf(lw*lw + lx*lx + ly*ly + lz*lz);
  float inv = 1.0f / fmaxf(n, 1e-8f);
  lw*=inv; lx*=inv; ly*=inv; lz*=inv;
  float xx=lx*lx, yy=ly*ly, zz=lz*lz;
  float xy=lx*ly, xz=lx*lz, yz=ly*lz;
  float wx=lw*lx, wy=lw*ly, wz=lw*lz;
  float m[9];
  m[0]=1.0f-2.0f*(yy+zz); m[1]=2.0f*(xy-wz);      m[2]=2.0f*(xz+wy);
  m[3]=2.0f*(xy+wz);      m[4]=1.0f-2.0f*(xx+zz); m[5]=2.0f*(yz-wx);
  m[6]=2.0f*(xz-wy);      m[7]=2.0f*(yz+wx);      m[8]=1.0f-2.0f*(xx+yy);
  // new pos = parent R @ off + parent pos   (uses f.r BEFORE update)
  float np[3];
  #pragma unroll
  for (int i=0;i<3;i++)
    np[i] = f.r[3*i+0]*off[0] + f.r[3*i+1]*off[1] + f.r[3*i+2]*off[2] + f.p[i];
  // new R = parent R @ m
  float nr[9];
  #pragma unroll
  for (int i=0;i<3;i++) {
    #pragma unroll
    for (int k=0;k<3;k++)
      nr[3*i+k] = f.r[3*i+0]*m[k] + f.r[3*i+1]*m[3+k] + f.r[3*i+2]*m[6+k];
  }
  #pragma unroll
  for (int i=0;i<9;i++) f.r[i]=nr[i];
  f.p[0]=np[0]; f.p[1]=np[1]; f.p[2]=np[2];
  f.q[0]=q[0]; f.q[1]=q[1]; f.q[2]=q[2]; f.q[3]=q[3];
}

__global__ __launch_bounds__(256) void fk_loss_kernel(
    const float* __restrict__ ik,   // (32, 168, 4096)
    const float* __restrict__ dec,  // (32, 176, 4096)
    const float* __restrict__ tgt,  // (32, 176, 4096)
    const float* __restrict__ mean, // (176,)
    const float* __restrict__ stdv, // (176,)
    const float* __restrict__ offs, // (22, 3)
    float* __restrict__ out)
{
  __shared__ float s_mean[176];
  __shared__ float s_std[176];
  __shared__ float s_off[66];
  const int tid = threadIdx.x;
  for (int i = tid; i < 176; i += 256) { s_mean[i] = mean[i]; s_std[i] = stdv[i]; }
  for (int i = tid; i < 66; i += 256) s_off[i] = offs[i];
  __syncthreads();

  const int idx = blockIdx.x * 256 + tid;   // 0 .. 131071
  const int b = idx >> 12;                  // / 4096
  const int t = idx & 4095;
  const float* __restrict__ pik  = ik  + ((size_t)b * 168) * TDIM + t;
  const float* __restrict__ pdec = dec + ((size_t)b * 176) * TDIM + t;
  const float* __restrict__ ptgt = tgt + ((size_t)b * 176) * TDIM + t;

  float see_p = 0.f, see_m = 0.f, srg_p = 0.f, srg_m = 0.f;

  Fr fik, fdec, ftgt;

  // tgt root quat (set_root=False for target): channels 0..3, denormed
  float rq[4];
  #pragma unroll
  for (int c = 0; c < 4; c++) rq[c] = ptgt[c * TDIM] * s_std[c] + s_mean[c];

  // per-joint: load 4 quat channels for each stream, denorm, step, accumulate loss
#define LOADQ(qd, base, chbase, sbase)                                        \
  { _Pragma("unroll")                                                         \
    for (int c = 0; c < 4; c++)                                               \
      qd[c] = (base)[((chbase) + c) * TDIM] * s_std[(sbase) + c] + s_mean[(sbase) + c]; }

#define JOINT(j, IS_EE)                                                       \
  {                                                                           \
    float qi[4], qd[4], qt[4];                                                \
    LOADQ(qi, pik,  ((j) - 1) * 8, (j) * 8);                                  \
    LOADQ(qd, pdec, (j) * 8,       (j) * 8);                                  \
    LOADQ(qt, ptgt, (j) * 8,       (j) * 8);                                  \
    const float off[3] = { s_off[(j)*3], s_off[(j)*3+1], s_off[(j)*3+2] };    \
    step(fik,  qi, off);                                                      \
    step(fdec, qd, off);                                                      \
    step(ftgt, qt, off);                                                      \
    if (IS_EE) {                                                              \
      _Pragma("unroll")                                                       \
      for (int c = 0; c < 3; c++) { float d = fik.p[c] - ftgt.p[c]; see_p += d*d; } \
      _Pragma("unroll")                                                       \
      for (int c = 0; c < 9; c++) { float d = fik.r[c] - ftgt.r[c]; see_m += d*d; } \
    } else {                                                                  \
      _Pragma("unroll")                                                       \
      for (int c = 0; c < 3; c++) { float d = fdec.p[c] - fik.p[c]; srg_p += d*d; } \
      _Pragma("unroll")                                                       \
      for (int c = 0; c < 9; c++) { float d = fdec.r[c] - fik.r[c]; srg_m += d*d; } \
    }                                                                         \
  }

  // chain A: 0 -> 1 -> 2 -> 3 -> 4(EE)
  frame_root(fik, 1.f, 0.f, 0.f, 0.f);
  frame_root(fdec, 1.f, 0.f, 0.f, 0.f);
  frame_root(ftgt, rq[0], rq[1], rq[2], rq[3]);
  JOINT(1, false); JOINT(2, false); JOINT(3, false); JOINT(4, true);

  // chain B: 0 -> 5 -> 6 -> 7 -> 8(EE)
  frame_root(fik, 1.f, 0.f, 0.f, 0.f);
  frame_root(fdec, 1.f, 0.f, 0.f, 0.f);
  frame_root(ftgt, rq[0], rq[1], rq[2], rq[3]);
  JOINT(5, false); JOINT(6, false); JOINT(7, false); JOINT(8, true);

  // chain C: 0 -> 9 -> 10 -> 11 (branch) -> 12 -> 13(EE)
  frame_root(fik, 1.f, 0.f, 0.f, 0.f);
  frame_root(fdec, 1.f, 0.f, 0.f, 0.f);
  frame_root(ftgt, rq[0], rq[1], rq[2], rq[3]);
  JOINT(9, false); JOINT(10, false); JOINT(11, false);
  Fr sik = fik, sdec = fdec, stgt = ftgt;   // save state at joint 11
  JOINT(12, false); JOINT(13, true);

  // branch: 11 -> 14 -> 15 -> 16 -> 17(EE)
  fik = sik; fdec = sdec; ftgt = stgt;
  JOINT(14, false); JOINT(15, false); JOINT(16, false); JOINT(17, true);

  // branch: 11 -> 18 -> 19 -> 20 -> 21(EE)
  fik = sik; fdec = sdec; ftgt = stgt;
  JOINT(18, false); JOINT(19, false); JOINT(20, false); JOINT(21, true);

#undef JOINT
#undef LOADQ

  // per-thread weighted combine:
  // loss = see_p/(BT*15) + see_m/(BT*45) + 0.1*(srg_p/(BT*48) + srg_m/(BT*144))
  const float W1 = 1.0f / 1966080.0f;   // 131072*15
  const float W2 = 1.0f / 5898240.0f;   // 131072*45
  const float W3 = 0.1f / 6291456.0f;   // 131072*48
  const float W4 = 0.1f / 18874368.0f;  // 131072*144
  float val = see_p * W1 + see_m * W2 + srg_p * W3 + srg_m * W4;

  // block reduction
  __shared__ float red[256];
  red[tid] = val;
  __syncthreads();
  #pragma unroll
  for (int s = 128; s > 0; s >>= 1) {
    if (tid < s) red[tid] += red[tid + s];
    __syncthreads();
  }
  if (tid == 0) atomicAdd(out, red[0]);
}

extern "C" void kernel_launch(void* const* d_in, const int* in_sizes, int n_in,
                              void* d_out, int out_size, void* d_ws, size_t ws_size,
                              hipStream_t stream) {
  const float* ik   = (const float*)d_in[1];
  const float* dec  = (const float*)d_in[2];
  const float* tgt  = (const float*)d_in[3];
  const float* mean = (const float*)d_in[4];
  const float* stdv = (const float*)d_in[5];
  const float* offs = (const float*)d_in[6];
  float* out = (float*)d_out;

  hipMemsetAsync(out, 0, sizeof(float), stream);
  fk_loss_kernel<<<dim3(512), dim3(256), 0, stream>>>(ik, dec, tgt, mean, stdv, offs, out);
}

// Round 2
// 32.845 us; speedup vs baseline: 7.3597x; 7.3597x over previous
//
#include <hip/hip_runtime.h>

#define TDIM 4096
#define SBAR() __builtin_amdgcn_sched_barrier(0)

// frame layout: f[0..8]=R (row major), f[9..11]=pos, f[12..15]=parent raw quat
__device__ __forceinline__ void fk_step(float* __restrict__ f,
                                        const float* __restrict__ q,
                                        const float* __restrict__ off) {
  const float pw = f[12], px = f[13], py = f[14], pz = f[15];
  // loc = conj(parent_q) * q
  float lw = pw*q[0] + px*q[1] + py*q[2] + pz*q[3];
  float lx = pw*q[1] - px*q[0] - py*q[3] + pz*q[2];
  float ly = pw*q[2] + px*q[3] - py*q[0] - pz*q[1];
  float lz = pw*q[3] - px*q[2] + py*q[1] - pz*q[0];
  float n2 = lw*lw + lx*lx + ly*ly + lz*lz;
  float inv = rsqrtf(fmaxf(n2, 1e-16f));
  lw *= inv; lx *= inv; ly *= inv; lz *= inv;
  float xx = lx*lx, yy = ly*ly, zz = lz*lz;
  float xy = lx*ly, xz = lx*lz, yz = ly*lz;
  float wx = lw*lx, wy = lw*ly, wz = lw*lz;
  float m0 = 1.0f-2.0f*(yy+zz), m1 = 2.0f*(xy-wz),      m2 = 2.0f*(xz+wy);
  float m3 = 2.0f*(xy+wz),      m4 = 1.0f-2.0f*(xx+zz), m5 = 2.0f*(yz-wx);
  float m6 = 2.0f*(xz-wy),      m7 = 2.0f*(yz+wx),      m8 = 1.0f-2.0f*(xx+yy);
  // pos += parent R @ off  (parent R is f[0..8] before update)
  f[9]  += f[0]*off[0] + f[1]*off[1] + f[2]*off[2];
  f[10] += f[3]*off[0] + f[4]*off[1] + f[5]*off[2];
  f[11] += f[6]*off[0] + f[7]*off[1] + f[8]*off[2];
  // R = parent R @ m
  float r0 = f[0]*m0 + f[1]*m3 + f[2]*m6;
  float r1 = f[0]*m1 + f[1]*m4 + f[2]*m7;
  float r2 = f[0]*m2 + f[1]*m5 + f[2]*m8;
  float r3 = f[3]*m0 + f[4]*m3 + f[5]*m6;
  float r4 = f[3]*m1 + f[4]*m4 + f[5]*m7;
  float r5 = f[3]*m2 + f[4]*m5 + f[5]*m8;
  float r6 = f[6]*m0 + f[7]*m3 + f[8]*m6;
  float r7 = f[6]*m1 + f[7]*m4 + f[8]*m7;
  float r8 = f[6]*m2 + f[7]*m5 + f[8]*m8;
  f[0]=r0; f[1]=r1; f[2]=r2; f[3]=r3; f[4]=r4; f[5]=r5; f[6]=r6; f[7]=r7; f[8]=r8;
  f[12]=q[0]; f[13]=q[1]; f[14]=q[2]; f[15]=q[3];
}

__global__ __launch_bounds__(256) void fk_loss_kernel(
    const float* __restrict__ ik,   // (32, 168, 4096)
    const float* __restrict__ dec,  // (32, 176, 4096)
    const float* __restrict__ tgt,  // (32, 176, 4096)
    const float* __restrict__ mean, // (176,)
    const float* __restrict__ stdv, // (176,)
    const float* __restrict__ offs, // (22, 3)
    float* __restrict__ out)
{
  __shared__ float s_mean[176];
  __shared__ float s_std[176];
  __shared__ float s_off[66];
  __shared__ float s_wsum[4];
  const int tid = threadIdx.x;
  for (int i = tid; i < 176; i += 256) { s_mean[i] = mean[i]; s_std[i] = stdv[i]; }
  for (int i = tid; i < 66; i += 256) s_off[i] = offs[i];
  __syncthreads();

  const int idx = blockIdx.x * 256 + tid;   // 0 .. 131071
  const int b = idx >> 12;
  const int t = idx & 4095;
  const float* __restrict__ pik  = ik  + ((size_t)b * 168) * TDIM + t;
  const float* __restrict__ pdec = dec + ((size_t)b * 176) * TDIM + t;
  const float* __restrict__ ptgt = tgt + ((size_t)b * 176) * TDIM + t;

  float see_p = 0.f, see_m = 0.f, srg_p = 0.f, srg_m = 0.f;

  float fik[16], fdec[16], ftgt[16];
  float sik[16], sdec[16], stgt[16];
  float rq[4];

  // stage buffers: [0..3] ik raw, [4..7] dec raw, [8..11] tgt raw,
  //                [12..15] std, [16..19] mean, [20..22] off
  float A[23], B[23];

#define LOADST(buf, j)                                                         \
  { _Pragma("unroll")                                                          \
    for (int c = 0; c < 4; c++) buf[c]      = pik [(((j)-1)*8 + c) * TDIM];    \
    _Pragma("unroll")                                                          \
    for (int c = 0; c < 4; c++) buf[4 + c]  = pdec[(((j)*8)   + c) * TDIM];    \
    _Pragma("unroll")                                                          \
    for (int c = 0; c < 4; c++) buf[8 + c]  = ptgt[(((j)*8)   + c) * TDIM];    \
    _Pragma("unroll")                                                          \
    for (int c = 0; c < 4; c++) buf[12 + c] = s_std[(j)*8 + c];                \
    _Pragma("unroll")                                                          \
    for (int c = 0; c < 4; c++) buf[16 + c] = s_mean[(j)*8 + c];               \
    _Pragma("unroll")                                                          \
    for (int c = 0; c < 3; c++) buf[20 + c] = s_off[(j)*3 + c]; }

#define COMP(buf, IS_EE)                                                       \
  { float qi[4], qd[4], qt[4];                                                 \
    _Pragma("unroll")                                                          \
    for (int c = 0; c < 4; c++) {                                              \
      qi[c] = fmaf(buf[c],     buf[12+c], buf[16+c]);                          \
      qd[c] = fmaf(buf[4+c],   buf[12+c], buf[16+c]);                          \
      qt[c] = fmaf(buf[8+c],   buf[12+c], buf[16+c]);                          \
    }                                                                          \
    fk_step(fik,  qi, buf + 20);                                               \
    fk_step(fdec, qd, buf + 20);                                               \
    fk_step(ftgt, qt, buf + 20);                                               \
    if (IS_EE) {                                                               \
      _Pragma("unroll")                                                        \
      for (int c = 0; c < 3; c++) { float d = fik[9+c] - ftgt[9+c]; see_p = fmaf(d, d, see_p); } \
      _Pragma("unroll")                                                        \
      for (int c = 0; c < 9; c++) { float d = fik[c]   - ftgt[c];   see_m = fmaf(d, d, see_m); } \
    } else {                                                                   \
      _Pragma("unroll")                                                        \
      for (int c = 0; c < 3; c++) { float d = fdec[9+c] - fik[9+c]; srg_p = fmaf(d, d, srg_p); } \
      _Pragma("unroll")                                                        \
      for (int c = 0; c < 9; c++) { float d = fdec[c]   - fik[c];   srg_m = fmaf(d, d, srg_m); } \
    } }

#define RESET()                                                                \
  { _Pragma("unroll")                                                          \
    for (int c = 0; c < 16; c++) { fik[c] = 0.f; fdec[c] = 0.f; ftgt[c] = 0.f; } \
    fik[0]=fik[4]=fik[8]=1.f; fdec[0]=fdec[4]=fdec[8]=1.f; ftgt[0]=ftgt[4]=ftgt[8]=1.f; \
    fik[12]=1.f; fdec[12]=1.f;                                                 \
    ftgt[12]=rq[0]; ftgt[13]=rq[1]; ftgt[14]=rq[2]; ftgt[15]=rq[3]; }

#define SAVE()                                                                 \
  { _Pragma("unroll")                                                          \
    for (int c = 0; c < 16; c++) { sik[c]=fik[c]; sdec[c]=fdec[c]; stgt[c]=ftgt[c]; } }

#define RESTORE()                                                              \
  { _Pragma("unroll")                                                          \
    for (int c = 0; c < 16; c++) { fik[c]=sik[c]; fdec[c]=sdec[c]; ftgt[c]=stgt[c]; } }

  // ---- S0: prime pipeline ----
  float rqr[4], rqs[4], rqm[4];
  #pragma unroll
  for (int c = 0; c < 4; c++) { rqr[c] = ptgt[c * TDIM]; rqs[c] = s_std[c]; rqm[c] = s_mean[c]; }
  LOADST(A, 1);
  SBAR();
  // ---- S1 ----
  #pragma unroll
  for (int c = 0; c < 4; c++) rq[c] = fmaf(rqr[c], rqs[c], rqm[c]);
  RESET();
  LOADST(B, 2);  COMP(A, false); SBAR();             // joint 1
  LOADST(A, 3);  COMP(B, false); SBAR();             // joint 2
  LOADST(B, 4);  COMP(A, false); SBAR();             // joint 3
  LOADST(A, 5);  COMP(B, true);  RESET(); SBAR();    // joint 4 EE
  LOADST(B, 6);  COMP(A, false); SBAR();             // joint 5
  LOADST(A, 7);  COMP(B, false); SBAR();             // joint 6
  LOADST(B, 8);  COMP(A, false); SBAR();             // joint 7
  LOADST(A, 9);  COMP(B, true);  RESET(); SBAR();    // joint 8 EE
  LOADST(B, 10); COMP(A, false); SBAR();             // joint 9
  LOADST(A, 11); COMP(B, false); SBAR();             // joint 10
  LOADST(B, 12); COMP(A, false); SAVE(); SBAR();     // joint 11 (branch point)
  LOADST(A, 13); COMP(B, false); SBAR();             // joint 12
  LOADST(B, 14); COMP(A, true);  RESTORE(); SBAR();  // joint 13 EE
  LOADST(A, 15); COMP(B, false); SBAR();             // joint 14
  LOADST(B, 16); COMP(A, false); SBAR();             // joint 15
  LOADST(A, 17); COMP(B, false); SBAR();             // joint 16
  LOADST(B, 18); COMP(A, true);  RESTORE(); SBAR();  // joint 17 EE
  LOADST(A, 19); COMP(B, false); SBAR();             // joint 18
  LOADST(B, 20); COMP(A, false); SBAR();             // joint 19
  LOADST(A, 21); COMP(B, false); SBAR();             // joint 20
  COMP(A, true);                                     // joint 21 EE

#undef LOADST
#undef COMP
#undef RESET
#undef SAVE
#undef RESTORE

  // weights: see_p/(BT*15) + see_m/(BT*45) + 0.1*(srg_p/(BT*48) + srg_m/(BT*144))
  const float W1 = 1.0f / 1966080.0f;
  const float W2 = 1.0f / 5898240.0f;
  const float W3 = 0.1f / 6291456.0f;
  const float W4 = 0.1f / 18874368.0f;
  float val = see_p * W1 + see_m * W2 + srg_p * W3 + srg_m * W4;

  // wave reduce, then cross-wave via LDS, one atomic per block
  #pragma unroll
  for (int o = 32; o > 0; o >>= 1) val += __shfl_down(val, o, 64);
  const int wid = tid >> 6, lane = tid & 63;
  if (lane == 0) s_wsum[wid] = val;
  __syncthreads();
  if (tid == 0) atomicAdd(out, s_wsum[0] + s_wsum[1] + s_wsum[2] + s_wsum[3]);
}

extern "C" void kernel_launch(void* const* d_in, const int* in_sizes, int n_in,
                              void* d_out, int out_size, void* d_ws, size_t ws_size,
                              hipStream_t stream) {
  const float* ik   = (const float*)d_in[1];
  const float* dec  = (const float*)d_in[2];
  const float* tgt  = (const float*)d_in[3];
  const float* mean = (const float*)d_in[4];
  const float* stdv = (const float*)d_in[5];
  const float* offs = (const float*)d_in[6];
  float* out = (float*)d_out;

  hipMemsetAsync(out, 0, sizeof(float), stream);
  fk_loss_kernel<<<dim3(512), dim3(256), 0, stream>>>(ik, dec, tgt, mean, stdv, offs, out);
}